// Round 9
// baseline (313.120 us; speedup 1.0000x reference)
//
#include <hip/hip_runtime.h>
#include <stdint.h>

#define NTOK 2048
#define DIM  1024
#define HID  2048
#define NEXP 8
#define CAPE 768    // per-expert slab rows; E[cnt]=512, sigma~21 -> 12-sigma slack
#define RB   256    // router blocks inside fused pre-kernel
#define CBT  8192   // convert blocks per weight tensor (2M 8-elem granules / 256 thr)
#define MT   (CAPE / 128)   // m-tiles per expert = 6

typedef __attribute__((ext_vector_type(8))) short short8;
typedef __attribute__((ext_vector_type(4))) float floatx4;
typedef __attribute__((ext_vector_type(4))) unsigned short ushortx4;
typedef __attribute__((ext_vector_type(8))) unsigned short ushortx8;

static __device__ __forceinline__ unsigned short f2bf(float f) {
  uint32_t u = __builtin_bit_cast(uint32_t, f);
  u += 0x7fffu + ((u >> 16) & 1u);   // round-to-nearest-even
  return (unsigned short)(u >> 16);
}

// streaming fp32->bf16 convert of one 8-elem granule, non-temporal both ways
// (read-once / write-once: keep 192 MB of stream traffic out of L2/L3 so it
// doesn't evict Xe/He/bf16-weights).
static __device__ __forceinline__ void cvt_granule(const float* __restrict__ src,
                                                   unsigned short* __restrict__ dst,
                                                   size_t idx) {
  floatx4 a = __builtin_nontemporal_load((const floatx4*)src + 2 * idx);
  floatx4 b = __builtin_nontemporal_load((const floatx4*)src + 2 * idx + 1);
  ushortx8 o;
  o[0] = f2bf(a.x); o[1] = f2bf(a.y); o[2] = f2bf(a.z); o[3] = f2bf(a.w);
  o[4] = f2bf(b.x); o[5] = f2bf(b.y); o[6] = f2bf(b.z); o[7] = f2bf(b.w);
  __builtin_nontemporal_store(o, (ushortx8*)dst + idx);
}

// ---- fused pre: router + token-scatter + out-zero (blocks 0..RB-1)
//      + Wfc fp32->bf16 convert (blocks RB..RB+CBT-1)
// Dispatch-count surgery (r5-r8: ~100us of the total is never in any kernel,
// ~15us/boundary): scanpos is gone (per-expert slab + atomic cursor -> slab
// row known at routing time), gather is gone (the router wave scatters its
// own 2 tokens from L1-hot x), the big out-memset is gone (router wave zeroes
// its token's out row; combine's 2 atomic adds onto true zero are
// order-exact). 7 stream ops -> 4.
__global__ void __launch_bounds__(256) pre_kernel(const float* __restrict__ x,
                                                  const float* __restrict__ Wr,
                                                  const float* __restrict__ Wfc,
                                                  unsigned short* __restrict__ bfc,
                                                  int* __restrict__ ctrl,
                                                  float* __restrict__ wts,
                                                  int* __restrict__ afor,
                                                  unsigned short* __restrict__ Xe,
                                                  float* __restrict__ out) {
  if (blockIdx.x >= RB) {
    size_t idx = (size_t)(blockIdx.x - RB) * 256 + threadIdx.x;
    cvt_granule(Wfc, bfc, idx);
    return;
  }

  const int wave = threadIdx.x >> 6;
  const int lane = threadIdx.x & 63;
  if (blockIdx.x == 0 && threadIdx.x == 0) out[(size_t)NTOK * DIM] = 0.f;  // aux_loss

#pragma unroll
  for (int j = 0; j < 2; j++) {
    int t = blockIdx.x * 8 + wave * 2 + j;
    const float* xr = x + (size_t)t * DIM;
    float acc[NEXP];
#pragma unroll
    for (int e = 0; e < NEXP; e++) acc[e] = 0.f;
#pragma unroll
    for (int i = 0; i < 4; i++) {
      floatx4 v = ((const floatx4*)xr)[i * 64 + lane];
      int idx = (i * 64 + lane) * 4;
#pragma unroll
      for (int e = 0; e < NEXP; e++) {
        floatx4 w = *(const floatx4*)&Wr[e * DIM + idx];
        acc[e] += v.x * w.x + v.y * w.y + v.z * w.z + v.w * w.w;
      }
    }
#pragma unroll
    for (int e = 0; e < NEXP; e++) {
#pragma unroll
      for (int off = 32; off > 0; off >>= 1) acc[e] += __shfl_down(acc[e], off);
    }
    int s0 = 0, s1 = 0;
    if (lane == 0) {
      float mx = acc[0];
      for (int e = 1; e < NEXP; e++) mx = fmaxf(mx, acc[e]);
      float p[NEXP], s = 0.f;
      for (int e = 0; e < NEXP; e++) { p[e] = expf(acc[e] - mx); s += p[e]; }
      float inv = 1.f / s;
      for (int e = 0; e < NEXP; e++) p[e] *= inv;
      int i0 = 0; float p0 = p[0];
      for (int e = 1; e < NEXP; e++) if (p[e] > p0) { p0 = p[e]; i0 = e; }   // ties: lowest idx
      int i1 = -1; float p1 = -1.f;
      for (int e = 0; e < NEXP; e++) if (e != i0 && p[e] > p1) { p1 = p[e]; i1 = e; }
      float rn = 1.f / (p0 + p1 + 1e-8f);
      wts[2 * t] = p0 * rn; wts[2 * t + 1] = p1 * rn;
      int c0 = atomicAdd(&ctrl[i0], 1);
      int c1 = atomicAdd(&ctrl[i1], 1);
      s0 = i0 * CAPE + c0;
      s1 = i1 * CAPE + c1;
      afor[s0] = 2 * t;
      afor[s1] = 2 * t + 1;
    }
    s0 = __shfl(s0, 0);
    s1 = __shfl(s1, 0);

    // scatter token row to both expert slabs (x is L1-hot) + zero out row
    floatx4 z4 = {0.f, 0.f, 0.f, 0.f};
#pragma unroll
    for (int i = 0; i < 4; i++) {
      int g = i * 64 + lane;
      floatx4 v = ((const floatx4*)xr)[g];
      ushortx4 b;
      b.x = f2bf(v.x); b.y = f2bf(v.y); b.z = f2bf(v.z); b.w = f2bf(v.w);
      *(ushortx4*)(Xe + (size_t)s0 * DIM + 4 * g) = b;
      *(ushortx4*)(Xe + (size_t)s1 * DIM + 4 * g) = b;
      ((floatx4*)(out + (size_t)t * DIM))[g] = z4;
    }
  }
}

// -------- r0's measured-33us bf16 GEMM body (bf16 A AND B via gll) -----------
// Slab layout: expert e's rows live at [e*CAPE, e*CAPE+cnt[e]); no scan/base
// table. CVT=1 (gemm1): blockIdx.y >= MT are streaming-convert rider blocks
// for W_proj (HBM-bound) overlapping the L2/LDS-bound GEMM blocks.
// EPI=0: relu(C)^2 -> bf16 He.  EPI=1: fused combine — atomicAdd of
// wts[afor[row]] * acc into pre-zeroed out.
template <int K, int N, int EPI, int CVT>
__global__ void __launch_bounds__(256) gemm_kernel(const unsigned short* __restrict__ A,
                                                   const unsigned short* __restrict__ B,
                                                   unsigned short* __restrict__ Cbf,
                                                   float* __restrict__ outp,
                                                   const int* __restrict__ ctrl,
                                                   const int* __restrict__ afor,
                                                   const float* __restrict__ wts,
                                                   const float* __restrict__ cvt_src,
                                                   unsigned short* __restrict__ cvt_dst) {
  if (CVT && blockIdx.y >= MT) {
    int cb = (blockIdx.y - MT) * (gridDim.x * gridDim.z) + blockIdx.z * gridDim.x + blockIdx.x;
    size_t idx = (size_t)cb * 256 + threadIdx.x;
    cvt_granule(cvt_src, cvt_dst, idx);
    return;
  }

  const int e = blockIdx.z;
  const int cnt = ctrl[e];
  const int m0 = blockIdx.y * 128;
  if (m0 >= cnt) return;
  const int base = e * CAPE;
  const int n0 = blockIdx.x * 128;

  __shared__ __align__(16) unsigned short ldsA[128 * 64];
  __shared__ __align__(16) unsigned short ldsB[128 * 64];

  const int tid = threadIdx.x;
  const int lane = tid & 63;
  const int wave = tid >> 6;
  const int wm = wave & 1, wn = wave >> 1;

  const unsigned short* Ae = A + (size_t)(base + m0) * K;
  const unsigned short* Be = B + ((size_t)e * N + n0) * (size_t)K;

  const int rsub = lane >> 3;   // row within 8-row chunk
  const int sg = lane & 7;      // stored 16B group (swizzled)

  floatx4 acc[4][4];
  floatx4 zero = {0.f, 0.f, 0.f, 0.f};
#pragma unroll
  for (int i = 0; i < 4; i++)
#pragma unroll
    for (int j = 0; j < 4; j++) acc[i][j] = zero;

  for (int k0 = 0; k0 < K; k0 += 64) {
#pragma unroll
    for (int j = 0; j < 4; j++) {
      int c = wave * 4 + j;
      int rc = c * 8 + rsub;
      int g = sg ^ (rc & 7);
      const unsigned short* ga = Ae + (size_t)rc * K + k0 + g * 8;
      const unsigned short* gb = Be + (size_t)rc * K + k0 + g * 8;
      __builtin_amdgcn_global_load_lds((const __attribute__((address_space(1))) unsigned int*)ga,
                                       (__attribute__((address_space(3))) unsigned int*)&ldsA[c * 512],
                                       16, 0, 0);
      __builtin_amdgcn_global_load_lds((const __attribute__((address_space(1))) unsigned int*)gb,
                                       (__attribute__((address_space(3))) unsigned int*)&ldsB[c * 512],
                                       16, 0, 0);
    }
    __builtin_amdgcn_s_waitcnt(0x0f70);  // vmcnt(0)
    __syncthreads();

#pragma unroll
    for (int kk = 0; kk < 2; kk++) {
      int q = lane >> 4;
      int gk = kk * 4 + q;
      short8 af[4], bfr[4];
#pragma unroll
      for (int mi = 0; mi < 4; mi++) {
        int row = wm * 64 + mi * 16 + (lane & 15);
        af[mi] = *(const short8*)&ldsA[row * 64 + (gk ^ (row & 7)) * 8];
      }
#pragma unroll
      for (int ni = 0; ni < 4; ni++) {
        int row = wn * 64 + ni * 16 + (lane & 15);
        bfr[ni] = *(const short8*)&ldsB[row * 64 + (gk ^ (row & 7)) * 8];
      }
#pragma unroll
      for (int mi = 0; mi < 4; mi++)
#pragma unroll
        for (int ni = 0; ni < 4; ni++)
          acc[mi][ni] = __builtin_amdgcn_mfma_f32_16x16x32_bf16(af[mi], bfr[ni], acc[mi][ni], 0, 0, 0);
    }
    __syncthreads();
  }

  // epilogue: D row=(lane>>4)*4+reg, col=lane&15; mask stores past cnt.
  const int lm = lane >> 4;
  const int ln = lane & 15;
#pragma unroll
  for (int mi = 0; mi < 4; mi++) {
#pragma unroll
    for (int r = 0; r < 4; r++) {
      int row = m0 + wm * 64 + mi * 16 + lm * 4 + r;   // local row in expert slab
      if (row < cnt) {
        if (EPI == 0) {
#pragma unroll
          for (int ni = 0; ni < 4; ni++) {
            int col = n0 + wn * 64 + ni * 16 + ln;
            float v = fmaxf(acc[mi][ni][r], 0.f);
            v = v * v;
            Cbf[(size_t)(base + row) * N + col] = f2bf(v);
          }
        } else {
          int a = afor[base + row];
          float w = wts[a];
          size_t tok = (size_t)(a >> 1);
#pragma unroll
          for (int ni = 0; ni < 4; ni++) {
            int col = n0 + wn * 64 + ni * 16 + ln;
            atomicAdd(&outp[tok * DIM + col], w * acc[mi][ni][r]);
          }
        }
      }
    }
  }
}

extern "C" void kernel_launch(void* const* d_in, const int* in_sizes, int n_in,
                              void* d_out, int out_size, void* d_ws, size_t ws_size,
                              hipStream_t stream) {
  const float* x   = (const float*)d_in[0];
  const float* Wr  = (const float*)d_in[1];
  const float* Wfc = (const float*)d_in[2];
  const float* Wpr = (const float*)d_in[3];
  float* out = (float*)d_out;
  char* ws = (char*)d_ws;

  const size_t WELEMS = (size_t)NEXP * HID * DIM;  // 16,777,216 per weight tensor

  int*   ctrl = (int*)ws;                      // cursors/counts[8]
  float* wts  = (float*)(ws + 1024);           // 4096 floats (16 KB)
  int*   afor = (int*)(ws + 32768);            // NEXP*CAPE ints (24 KB)
  unsigned short* Wfcb = (unsigned short*)(ws + 131072);
  unsigned short* Wprb = Wfcb + WELEMS;
  unsigned short* Xe   = Wprb + WELEMS;               // [NEXP*CAPE x DIM] bf16 (12 MB)
  unsigned short* He   = Xe + (size_t)NEXP * CAPE * DIM;  // [NEXP*CAPE x HID] bf16 (24 MB)

  hipMemsetAsync(ctrl, 0, 32, stream);         // only the 8 cursors

  pre_kernel<<<RB + CBT, 256, 0, stream>>>(x, Wr, Wfc, Wfcb, ctrl, wts, afor, Xe, out);

  // gemm1: y slots [0,MT) = GEMM tiles, [MT,MT+64) = 8192 W_proj convert riders
  gemm_kernel<DIM, HID, 0, 1><<<dim3(HID / 128, MT + 64, NEXP), 256, 0, stream>>>(
      Xe, Wfcb, He, nullptr, ctrl, nullptr, nullptr, Wpr, Wprb);
  // gemm2: fused combine (atomicAdd into out)
  gemm_kernel<HID, DIM, 1, 0><<<dim3(DIM / 128, MT, NEXP), 256, 0, stream>>>(
      He, Wprb, nullptr, out, ctrl, afor, wts, nullptr, nullptr);
}